// Round 9
// baseline (488.263 us; speedup 1.0000x reference)
//
#include <hip/hip_runtime.h>
#include <hip/hip_cooperative_groups.h>

namespace cg = cooperative_groups;

// GGNN on MI355X — R9: ONE cooperative kernel (6 dispatches had ~13us launch
// overhead each = ~80us). Phases: P0 cvt+Wf=Wih@W0/W1 precompute+dtype detect
// -> P1 dst-bucket histogram -> P2 scan -> P3 place -> P4 CSR+gather ->
// P5 MFMA GRU+head with Wf/Wout staged in LDS and TRANSPOSED gates
// (MFMA(W,S): A/B frag layouts are symmetric) so h assembles into the head
// A-layout with 16 shfls — no LDS transposes. Fallback: 5 phase launches.

typedef __bf16 bf16x8 __attribute__((ext_vector_type(8)));
typedef float  f32x4  __attribute__((ext_vector_type(4)));
typedef int    i32x4  __attribute__((ext_vector_type(4)));
typedef unsigned u32x2 __attribute__((ext_vector_type(2)));

#define MFMA16 __builtin_amdgcn_mfma_f32_16x16x32_bf16
#define NN    100000
#define EE    1000000
#define BB    512      // buckets = blocks; bucket = dst/196 (magic div)
#define NPB   196      // nodes per bucket
#define ECAP  2432     // bucket region cap (mean 1960, +10 sigma)
#define DCAP  48       // per-node degree cap
#define CSTRD 49
#define CHUNK 2048     // edges per block in hist/place (512*2048 >= 1e6)
#define WSTR  64       // LDS weight row stride (elems)
#define BIASOFF 51200  // 400 rows * 64 * 2B ; biases (640 f32) after
#define SMEMSZ (BIASOFF + 2560)
#define DMAGIC 21913099ULL  // ceil(2^32/196); exact for d < 39M

__device__ __forceinline__ float sigmoidf_(float x){ return 1.0f/(1.0f+__expf(-x)); }
__device__ __forceinline__ float tanhf_(float x){ return 1.0f - 2.0f/(__expf(2.0f*x)+1.0f); }
__device__ __forceinline__ unsigned packbf(float a, float b){
    union { __bf16 h[2]; unsigned u; } p; p.h[0]=(__bf16)a; p.h[1]=(__bf16)b; return p.u;
}
__device__ __forceinline__ float unpk(unsigned u, int hi){
    union { unsigned u; float f; } c; c.u = (hi ? (u & 0xffff0000u) : (u << 16)); return c.f;
}

// mode: 99 = cooperative (grid.sync between phases); 0..4 = single phase.
__global__ __launch_bounds__(512, 4) void k_all(
        int mode,
        const float* __restrict__ feat, const int* __restrict__ src,
        const int* __restrict__ dst, const unsigned char* __restrict__ et,
        const float* __restrict__ w0, const float* __restrict__ b0,
        const float* __restrict__ w1, const float* __restrict__ b1,
        const float* __restrict__ wih, const float* __restrict__ whh,
        const float* __restrict__ bih, const float* __restrict__ bhh,
        const float* __restrict__ wout, const float* __restrict__ bout,
        __bf16* __restrict__ featb, int* __restrict__ region,
        int* __restrict__ hist, int* __restrict__ blockBase,
        int* __restrict__ bucketCnt, __bf16* __restrict__ wbn,
        float* __restrict__ biasv, int* __restrict__ flag,
        float* __restrict__ out) {
    __shared__ __align__(16) char smem[SMEMSZ];
    int* s32 = (int*)smem;
    int b = blockIdx.x, tid = threadIdx.x;
    int lane = tid & 63, wave = tid >> 6;
    int L = lane & 15, q = lane >> 4;

    // ================= P0: init =================
    if (mode == 99 || mode == 0) {
        if (b < 49) {            // Wf0/Wf1 = Wih@W0/W1, bv = Wih@b, bias arrays
            int idx = b * 512 + tid;
            if (idx < 12288) {
                int g = idx >> 6, h = idx & 63;
                float a = 0.f;
                for (int m = 0; m < 64; m++) a += wih[g*64+m] * w0[m*64+h];
                wbn[idx] = (__bf16)a;
            } else if (idx < 24576) {
                int j = idx - 12288; int g = j >> 6, h = j & 63;
                float a = 0.f;
                for (int m = 0; m < 64; m++) a += wih[g*64+m] * w1[m*64+h];
                wbn[idx] = (__bf16)a;
            } else if (idx < 24768) {
                int g = idx - 24576;
                float a0 = 0.f, a1 = 0.f;
                for (int m = 0; m < 64; m++) {
                    float w = wih[g*64+m]; a0 += w*b0[m]; a1 += w*b1[m];
                }
                biasv[192+g] = a0; biasv[384+g] = a1;
            } else if (idx < 24960) {
                int g = idx - 24768;
                biasv[g] = (g < 128) ? (bih[g] + bhh[g]) : bih[g];
            } else if (idx < 25024) {
                int g2 = idx - 24960;
                biasv[576+g2] = bhh[128+g2];
            }
        } else if (b < 75) {     // Whh/Wout -> bf16 in wbn
            int i = (b - 49) * 512 + tid;
            if (i < 12288) wbn[24576 + i] = (__bf16)whh[i];
            else if (i < 13312) wbn[36864 + i - 12288] = (__bf16)wout[i - 12288];
        } else if (b == 75) {    // edge_types dtype detect (64KB scan)
            const i32x4* p = (const i32x4*)et + tid * 8;  // 128B/thread
            unsigned acc = 0;
            #pragma unroll
            for (int j = 0; j < 8; j++) {
                i32x4 w = p[j];
                acc |= (unsigned)(w[0] | w[1] | w[2] | w[3]) & 0xffffff00u;
            }
            unsigned long long m = __ballot(acc != 0);
            if (lane == 0) s32[wave] = (m != 0ULL);
            __syncthreads();
            if (tid == 0) {
                int f = 0;
                for (int i = 0; i < 8; i++) f |= s32[i];
                *flag = f;
            }
        } else {                 // features f32 -> bf16
            long i0 = (long)(b - 76) * 512 + tid;
            for (long i = i0; i < (long)NN*16; i += 436*512) {
                f32x4 v = *(const f32x4*)(feat + i*4);
                union { __bf16 e[4]; unsigned long long u; } o;
                #pragma unroll
                for (int j = 0; j < 4; j++) o.e[j] = (__bf16)v[j];
                *(unsigned long long*)(featb + i*4) = o.u;
            }
        }
    }
    if (mode == 99) cg::this_grid().sync();

    // ================= P1: bucket histogram =================
    if (mode == 99 || mode == 1) {
        s32[tid] = 0;
        __syncthreads();
        long base = (long)b * CHUNK;
        #pragma unroll
        for (int k = 0; k < 4; k++) {
            long e = base + k*512 + tid;
            if (e < EE) {
                unsigned d = (unsigned)dst[e];
                int bk = (int)((d * DMAGIC) >> 32);
                atomicAdd(&s32[bk], 1);
            }
        }
        __syncthreads();
        hist[b*BB + tid] = s32[tid];
    }
    if (mode == 99) cg::this_grid().sync();

    // ================= P2: per-bucket scan over chunk blocks =================
    if (mode == 99 || mode == 2) {
        int v = hist[tid*BB + b];
        int x = v;
        #pragma unroll
        for (int o = 1; o < 64; o <<= 1) {
            int y = __shfl_up(x, o);
            if (lane >= o) x += y;
        }
        if (lane == 63) s32[wave] = x;
        __syncthreads();
        if (tid == 0) {
            int a = 0;
            for (int i = 0; i < 8; i++) { int t2 = s32[i]; s32[i] = a; a += t2; }
        }
        __syncthreads();
        int excl = x - v + s32[wave];
        blockBase[tid*BB + b] = excl;
        if (tid == 511) bucketCnt[b] = excl + v;
    }
    if (mode == 99) cg::this_grid().sync();

    // ================= P3: place edges =================
    if (mode == 99 || mode == 3) {
        s32[tid] = blockBase[b*BB + tid];
        __syncthreads();
        int eshift = (*flag) ? 0 : 2;
        long base = (long)b * CHUNK;
        #pragma unroll
        for (int k = 0; k < 4; k++) {
            long e = base + k*512 + tid;
            if (e < EE) {
                int s = src[e];
                unsigned d = (unsigned)dst[e];
                int t = et[(size_t)e << eshift] ? 1 : 0;
                int bk = (int)((d * DMAGIC) >> 32);
                int nl = (int)d - bk * NPB;
                int r = atomicAdd(&s32[bk], 1);
                if (r < ECAP) region[bk*ECAP + r] = (nl << 18) | (t << 17) | s;
            }
        }
    }
    if (mode == 99) cg::this_grid().sync();

    // ================= P4: CSR + gather; P5: MFMA tail =================
    if (mode == 99 || mode == 4) {
        int* ncnt = s32;            // 256 ints
        int* csr  = s32 + 256;      // 196*49 ints
        if (tid < 256) ncnt[tid] = 0;
        __syncthreads();
        int cntE = min(bucketCnt[b], ECAP);
        for (int i = tid; i < cntE; i += 512) {
            int rec = region[b*ECAP + i];
            int nl = rec >> 18;
            int r = atomicAdd(&ncnt[nl], 1);
            if (r < DCAP) csr[nl*CSTRD + r] = rec & 0x3ffff;
        }
        __syncthreads();

        bf16x8 fS1[2][2], fS0[2][2], fAf[2][2];
        int cntP[2], c1P[2];
        #pragma unroll
        for (int p = 0; p < 2; p++) {
            int nl = p*128 + wave*16 + L;
            int cnt = (nl < NPB) ? min(ncnt[nl], DCAP) : 0;
            float sA[16], s1[16];
            #pragma unroll
            for (int j = 0; j < 16; j++) { sA[j] = 0.f; s1[j] = 0.f; }
            int c1 = 0, i = 0;
            for (; i + 4 <= cnt; i += 4) {
                int e4[4];
                #pragma unroll
                for (int j = 0; j < 4; j++) e4[j] = csr[nl*CSTRD + i + j];
                bf16x8 ra[4], rb[4];
                #pragma unroll
                for (int j = 0; j < 4; j++) {
                    const __bf16* row = featb + (long)(e4[j] & 0x1ffff) * 64;
                    ra[j] = *(const bf16x8*)(row + q*8);
                    rb[j] = *(const bf16x8*)(row + 32 + q*8);
                }
                #pragma unroll
                for (int j = 0; j < 4; j++) {
                    int t = (e4[j] >> 17) & 1; c1 += t;
                    float ft = (float)t;
                    #pragma unroll
                    for (int k = 0; k < 8; k++) {
                        float va = (float)ra[j][k], wa = (float)rb[j][k];
                        sA[k] += va;      sA[8+k] += wa;
                        s1[k] += ft*va;   s1[8+k] += ft*wa;
                    }
                }
            }
            for (; i < cnt; i++) {
                int ea = csr[nl*CSTRD + i];
                const __bf16* row = featb + (long)(ea & 0x1ffff) * 64;
                bf16x8 a0 = *(const bf16x8*)(row + q*8);
                bf16x8 a1 = *(const bf16x8*)(row + 32 + q*8);
                int ta = (ea >> 17) & 1; c1 += ta;
                float fa = (float)ta;
                #pragma unroll
                for (int k = 0; k < 8; k++) {
                    float va = (float)a0[k], wa = (float)a1[k];
                    sA[k] += va;      sA[8+k] += wa;
                    s1[k] += fa*va;   s1[8+k] += fa*wa;
                }
            }
            #pragma unroll
            for (int ch = 0; ch < 2; ch++) {
                union { bf16x8 v; __bf16 e[8]; } u0, u1;
                #pragma unroll
                for (int j = 0; j < 8; j++) {
                    float v1 = s1[ch*8+j];
                    u1.e[j] = (__bf16)v1;
                    u0.e[j] = (__bf16)(sA[ch*8+j] - v1);
                }
                fS1[p][ch] = u1.v; fS0[p][ch] = u0.v;
            }
            long nodeC = (long)b*NPB + nl; if (nodeC >= NN) nodeC = NN-1;
            const __bf16* fr = featb + nodeC*64;
            fAf[p][0] = *(const bf16x8*)(fr + q*8);
            fAf[p][1] = *(const bf16x8*)(fr + 32 + q*8);
            cntP[p] = cnt; c1P[p] = c1;
        }
        __syncthreads();   // csr dead

        // ---- stage Wf0/Wf1/Wout + biases into LDS ----
        {
            unsigned* ldw = (unsigned*)smem;
            const unsigned* gw = (const unsigned*)wbn;
            for (int i = tid; i < 12800; i += 512)
                ldw[i] = (i < 12288) ? gw[i] : gw[18432 + (i - 12288)];
            float* bl = (float*)(smem + BIASOFF);
            for (int i = tid; i < 640; i += 512) bl[i] = biasv[i];
        }
        __syncthreads();
        const __bf16* ldsW = (const __bf16*)smem;
        const float*  bl   = (const float*)(smem + BIASOFF);
        const __bf16* whhg = wbn + 24576;
        f32x4 zz = {0.f,0.f,0.f,0.f};

        #pragma unroll
        for (int p = 0; p < 2; p++) {
            float fc1 = (float)c1P[p], fc0 = (float)(cntP[p] - c1P[p]);
            long nodeC = (long)b*NPB + p*128 + wave*16 + L;
            if (nodeC >= NN) nodeC = NN-1;
            unsigned hp[4][2];
            #pragma unroll
            for (int nb = 0; nb < 4; nb++) {
                int rb_ = nb*16 + L;
                f32x4 aR = zz, aZ = zz, aIN = zz, aHN = zz;
                // gate r (row rb_), z (+64), n (+128)
                #pragma unroll
                for (int g = 0; g < 3; g++) {
                    int row = g*64 + rb_;
                    bf16x8 w0a = *(const bf16x8*)(ldsW + row*WSTR + q*8);
                    bf16x8 w0b = *(const bf16x8*)(ldsW + row*WSTR + 32 + q*8);
                    bf16x8 w1a = *(const bf16x8*)(ldsW + (192+row)*WSTR + q*8);
                    bf16x8 w1b = *(const bf16x8*)(ldsW + (192+row)*WSTR + 32 + q*8);
                    bf16x8 wha = *(const bf16x8*)(whhg + row*64 + q*8);
                    bf16x8 whb = *(const bf16x8*)(whhg + row*64 + 32 + q*8);
                    if (g == 0) {
                        aR = MFMA16(w0a, fS1[p][0], aR,0,0,0);
                        aR = MFMA16(w0b, fS1[p][1], aR,0,0,0);
                        aR = MFMA16(w1a, fS0[p][0], aR,0,0,0);
                        aR = MFMA16(w1b, fS0[p][1], aR,0,0,0);
                        aR = MFMA16(wha, fAf[p][0], aR,0,0,0);
                        aR = MFMA16(whb, fAf[p][1], aR,0,0,0);
                    } else if (g == 1) {
                        aZ = MFMA16(w0a, fS1[p][0], aZ,0,0,0);
                        aZ = MFMA16(w0b, fS1[p][1], aZ,0,0,0);
                        aZ = MFMA16(w1a, fS0[p][0], aZ,0,0,0);
                        aZ = MFMA16(w1b, fS0[p][1], aZ,0,0,0);
                        aZ = MFMA16(wha, fAf[p][0], aZ,0,0,0);
                        aZ = MFMA16(whb, fAf[p][1], aZ,0,0,0);
                    } else {
                        aIN = MFMA16(w0a, fS1[p][0], aIN,0,0,0);
                        aIN = MFMA16(w0b, fS1[p][1], aIN,0,0,0);
                        aIN = MFMA16(w1a, fS0[p][0], aIN,0,0,0);
                        aIN = MFMA16(w1b, fS0[p][1], aIN,0,0,0);
                        aHN = MFMA16(wha, fAf[p][0], aHN,0,0,0);
                        aHN = MFMA16(whb, fAf[p][1], aHN,0,0,0);
                    }
                }
                int o4 = nb*16 + q*4;
                f32x4 bAr  = *(const f32x4*)(bl + o4);
                f32x4 bAz  = *(const f32x4*)(bl + 64 + o4);
                f32x4 bAn  = *(const f32x4*)(bl + 128 + o4);
                f32x4 v0r  = *(const f32x4*)(bl + 192 + o4);
                f32x4 v0z  = *(const f32x4*)(bl + 256 + o4);
                f32x4 v0n  = *(const f32x4*)(bl + 320 + o4);
                f32x4 v1r  = *(const f32x4*)(bl + 384 + o4);
                f32x4 v1z  = *(const f32x4*)(bl + 448 + o4);
                f32x4 v1n  = *(const f32x4*)(bl + 512 + o4);
                f32x4 bhnv = *(const f32x4*)(bl + 576 + o4);
                u32x2 fw = *(const u32x2*)(featb + nodeC*64 + o4);
                float fvv[4] = { unpk(fw[0],0), unpk(fw[0],1), unpk(fw[1],0), unpk(fw[1],1) };
                float hv[4];
                #pragma unroll
                for (int r = 0; r < 4; r++) {
                    float rv = sigmoidf_(aR[r] + fc1*v0r[r] + fc0*v1r[r] + bAr[r]);
                    float zv = sigmoidf_(aZ[r] + fc1*v0z[r] + fc0*v1z[r] + bAz[r]);
                    float nv = tanhf_(aIN[r] + fc1*v0n[r] + fc0*v1n[r] + bAn[r]
                                      + rv*(aHN[r] + bhnv[r]));
                    hv[r] = (1.0f - zv)*nv + zv*fvv[r];
                }
                hp[nb][0] = packbf(hv[0], hv[1]);
                hp[nb][1] = packbf(hv[2], hv[3]);
            }
            // head: assemble h A-frags via shfl (no LDS)
            bf16x8 Ah[2];
            int l0 = L + 16*(2*(q&1));
            int l1 = l0 + 16;
            int sel = q >> 1;
            #pragma unroll
            for (int ch = 0; ch < 2; ch++) {
                unsigned dw[4];
                unsigned a0 = __shfl((int)hp[ch*2][0], l0), b0v = __shfl((int)hp[ch*2+1][0], l0);
                dw[0] = sel ? b0v : a0;
                unsigned a1 = __shfl((int)hp[ch*2][1], l0), b1v = __shfl((int)hp[ch*2+1][1], l0);
                dw[1] = sel ? b1v : a1;
                unsigned a2 = __shfl((int)hp[ch*2][0], l1), b2v = __shfl((int)hp[ch*2+1][0], l1);
                dw[2] = sel ? b2v : a2;
                unsigned a3 = __shfl((int)hp[ch*2][1], l1), b3v = __shfl((int)hp[ch*2+1][1], l1);
                dw[3] = sel ? b3v : a3;
                union { unsigned u[4]; bf16x8 v; } c;
                c.u[0]=dw[0]; c.u[1]=dw[1]; c.u[2]=dw[2]; c.u[3]=dw[3];
                Ah[ch] = c.v;
            }
            bf16x8 Bo0 = *(const bf16x8*)(ldsW + (384+L)*WSTR + q*8);
            bf16x8 Bo1 = *(const bf16x8*)(ldsW + (384+L)*WSTR + 32 + q*8);
            f32x4 o = zz;
            o = MFMA16(Ah[0], Bo0, o,0,0,0);
            o = MFMA16(Ah[1], Bo1, o,0,0,0);
            float bo = bout[L];
            #pragma unroll
            for (int r = 0; r < 4; r++) {
                int nloc = p*128 + wave*16 + q*4 + r;
                long node = (long)b*NPB + nloc;
                if (nloc < NPB && node < NN) out[node*16 + L] = o[r] + bo;
            }
        }
    }
}

extern "C" void kernel_launch(void* const* d_in, const int* in_sizes, int n_in,
                              void* d_out, int out_size, void* d_ws, size_t ws_size,
                              hipStream_t stream) {
    const float* feat = (const float*)d_in[0];
    const int*   src  = (const int*)d_in[1];
    const int*   dst  = (const int*)d_in[2];
    const unsigned char* et = (const unsigned char*)d_in[3];
    const float* w0   = (const float*)d_in[4];
    const float* b0   = (const float*)d_in[5];
    const float* w1   = (const float*)d_in[6];
    const float* b1   = (const float*)d_in[7];
    const float* wih  = (const float*)d_in[8];
    const float* whh  = (const float*)d_in[9];
    const float* bih  = (const float*)d_in[10];
    const float* bhh  = (const float*)d_in[11];
    const float* wout = (const float*)d_in[12];
    const float* bout = (const float*)d_in[13];
    float* out = (float*)d_out;

    char* ws = (char*)d_ws;
    __bf16* featb     = (__bf16*)(ws);
    int*    region    = (int*)(ws + 12800000);
    int*    hist      = (int*)(ws + 17780736);
    int*    blockBase = (int*)(ws + 18829312);
    int*    bucketCnt = (int*)(ws + 19877888);
    __bf16* wbn       = (__bf16*)(ws + 19879936);
    float*  biasv     = (float*)(ws + 19955712);
    int*    flag      = (int*)(ws + 19958272);

    int mode = 99;
    void* kargs[] = { &mode, &feat, &src, &dst, &et, &w0, &b0, &w1, &b1,
                      &wih, &whh, &bih, &bhh, &wout, &bout,
                      &featb, &region, &hist, &blockBase, &bucketCnt,
                      &wbn, &biasv, &flag, &out };
    hipError_t err = hipLaunchCooperativeKernel((const void*)k_all, dim3(BB),
                                                dim3(512), kargs, 0, stream);
    if (err != hipSuccess) {
        // fallback: 5 ordinary phase launches (same kernel, phase modes)
        (void)hipGetLastError();  // clear sticky error
        for (int ph = 0; ph < 5; ph++) {
            k_all<<<BB, 512, 0, stream>>>(ph, feat, src, dst, et, w0, b0, w1, b1,
                                          wih, whh, bih, bhh, wout, bout,
                                          featb, region, hist, blockBase,
                                          bucketCnt, wbn, biasv, flag, out);
        }
    }
}

// Round 10
// 309.690 us; speedup vs baseline: 1.5766x; 1.5766x over previous
//
#include <hip/hip_runtime.h>

// GGNN on MI355X. N=100000, E=1000000, H=M=64, C=16.
// R9 post-mortem: coop kernel spilled ~512B/thread (launch_bounds reg clamp +
// two live node-tiles) -> 160MB scratch writes, 488us. R10: revert to lean
// kernels, 4 launches:
//   k_init : dtype detect + Wf=Wih@W0/W1 + bias precompute + Whh/Wout cvt
//            + feature f32->bf16 + dst-bucket histogram (blockIdx partition)
//   k_place: per-block scan of hist rows (<beta) + LDS-cursor edge placement;
//            block NB-1 emits bucketCnt
//   k_g    : per-bucket CSR + x4-unrolled fp32 gather -> s1b/s0b/cc (R7 shape)
//   k_mm2  : streaming GRU+head tail: Wf0/Wf1/Wout staged in LDS (stride 68,
//            conflict-free), transposed gates (MFMA(W,S)), h->head via shfl.

typedef __bf16 bf16x8 __attribute__((ext_vector_type(8)));
typedef float  f32x4  __attribute__((ext_vector_type(4)));
typedef int    i32x4  __attribute__((ext_vector_type(4)));
typedef unsigned u32x2 __attribute__((ext_vector_type(2)));

#define MFMA16 __builtin_amdgcn_mfma_f32_16x16x32_bf16
#define NN    100000
#define EE    1000000
#define BB    782      // buckets (dst >> 7)
#define NPB   128      // nodes per bucket
#define ECAP  1600     // bucket region cap (mean 1280, +9 sigma)
#define DCAP  48       // per-node degree cap
#define CSTRD 49       // CSR LDS stride (ints)
#define NB    245      // hist/place blocks (4096 edges each)
#define WSTR  68       // LDS weight row stride (bf16 elems) — conflict-free

__device__ __forceinline__ float sigmoidf_(float x){ return 1.0f/(1.0f+__expf(-x)); }
__device__ __forceinline__ float tanhf_(float x){ return 1.0f - 2.0f/(__expf(2.0f*x)+1.0f); }
__device__ __forceinline__ unsigned packbf(float a, float b){
    union { __bf16 h[2]; unsigned u; } p; p.h[0]=(__bf16)a; p.h[1]=(__bf16)b; return p.u;
}
__device__ __forceinline__ float unpk(unsigned u, int hi){
    union { unsigned u; float f; } c; c.u = (hi ? (u & 0xffff0000u) : (u << 16)); return c.f;
}

// ---- k_init: detect / Wf+bias precompute / Whh+Wout cvt / feat cvt / hist ----
__global__ __launch_bounds__(512) void k_init(
        const unsigned char* __restrict__ et, const float* __restrict__ feat,
        const int* __restrict__ dst,
        const float* __restrict__ w0, const float* __restrict__ b0,
        const float* __restrict__ w1, const float* __restrict__ b1,
        const float* __restrict__ wih, const float* __restrict__ whh,
        const float* __restrict__ bih, const float* __restrict__ bhh,
        const float* __restrict__ wout,
        __bf16* __restrict__ featb, __bf16* __restrict__ wbn,
        float* __restrict__ biasv, int* __restrict__ hist,
        int* __restrict__ flag) {
    __shared__ int s32[BB];
    int b = blockIdx.x, tid = threadIdx.x;
    if (b == 0) {
        // dtype detect: flag=1 iff any nonzero byte at offset%4!=0 in 64KB
        const i32x4* p = (const i32x4*)et + tid * 8;  // 128B/thread
        unsigned acc = 0;
        #pragma unroll
        for (int j = 0; j < 8; j++) {
            i32x4 w = p[j];
            acc |= (unsigned)(w[0] | w[1] | w[2] | w[3]) & 0xffffff00u;
        }
        unsigned long long m = __ballot(acc != 0);
        if ((tid & 63) == 0) s32[tid >> 6] = (m != 0ULL);
        __syncthreads();
        if (tid == 0) {
            int f = 0;
            for (int i = 0; i < 8; i++) f |= s32[i];
            *flag = f;
        }
        return;
    }
    if (b < 50) {   // Wf0/Wf1 = Wih@W0/W1 (bf16); bv0/bv1 = Wih@b; bias arrays
        int idx = (b - 1) * 512 + tid;
        if (idx < 12288) {
            int g = idx >> 6, h = idx & 63;
            float a = 0.f;
            for (int m = 0; m < 64; m++) a += wih[g*64+m] * w0[m*64+h];
            wbn[idx] = (__bf16)a;
        } else if (idx < 24576) {
            int j = idx - 12288; int g = j >> 6, h = j & 63;
            float a = 0.f;
            for (int m = 0; m < 64; m++) a += wih[g*64+m] * w1[m*64+h];
            wbn[idx] = (__bf16)a;
        } else if (idx < 24768) {
            int g = idx - 24576;
            float a0 = 0.f, a1 = 0.f;
            for (int m = 0; m < 64; m++) {
                float w = wih[g*64+m]; a0 += w*b0[m]; a1 += w*b1[m];
            }
            biasv[192+g] = a0; biasv[384+g] = a1;
        } else if (idx < 24960) {
            int g = idx - 24768;   // [0:128)=r,z combined; [128:192)=bih_n
            biasv[g] = (g < 128) ? (bih[g] + bhh[g]) : bih[g];
        } else if (idx < 25024) {
            int g2 = idx - 24960;
            biasv[576+g2] = bhh[128+g2];   // bhn
        }
        return;
    }
    if (b < 76) {   // Whh (bf16) + Wout (bf16)
        int i = (b - 50) * 512 + tid;
        if (i < 12288)      wbn[24576 + i] = (__bf16)whh[i];
        else if (i < 13312) wbn[36864 + i - 12288] = (__bf16)wout[i - 12288];
        return;
    }
    if (b < 76 + NB) {   // bucket histogram, 4096 edges/block
        int blk = b - 76;
        for (int i = tid; i < BB; i += 512) s32[i] = 0;
        __syncthreads();
        long base = (long)blk * 4096;
        #pragma unroll
        for (int k = 0; k < 8; k++) {
            long e = base + k*512 + tid;
            if (e < EE) atomicAdd(&s32[((unsigned)dst[e]) >> 7], 1);
        }
        __syncthreads();
        for (int i = tid; i < BB; i += 512) hist[blk*BB + i] = s32[i];
        return;
    }
    // features f32 -> bf16, 8 elems/thread
    long i0 = ((long)(b - 76 - NB) * 512 + tid) * 8;
    if (i0 >= (long)NN * 64) return;
    f32x4 v0 = *(const f32x4*)(feat + i0);
    f32x4 v1 = *(const f32x4*)(feat + i0 + 4);
    union { __bf16 e[8]; i32x4 u; } o;
    #pragma unroll
    for (int j = 0; j < 4; j++) { o.e[j] = (__bf16)v0[j]; o.e[4+j] = (__bf16)v1[j]; }
    *(i32x4*)(featb + i0) = o.u;
}

// ---- k_place: scan hist rows < beta (register-accumulated) + place edges ----
__global__ __launch_bounds__(512) void k_place(
        const int* __restrict__ src, const int* __restrict__ dst,
        const unsigned char* __restrict__ et, const int* __restrict__ flag,
        const int* __restrict__ hist, int* __restrict__ region,
        int* __restrict__ bucketCnt) {
    __shared__ int cur[BB];
    int beta = blockIdx.x, tid = threadIdx.x;
    // exclusive prefix over blocks: thread owns buckets tid, tid+512
    int a0 = 0, a1 = 0;
    int i1 = tid + 512;
    for (int r = 0; r < beta; r++) {
        a0 += hist[r*BB + tid];
        if (i1 < BB) a1 += hist[r*BB + i1];
    }
    cur[tid] = a0;
    if (i1 < BB) cur[i1] = a1;
    __syncthreads();
    int eshift = (*flag) ? 0 : 2;  // byte stride: 1 (bool) or 4 (int32 LSB)
    long base = (long)beta * 4096;
    #pragma unroll
    for (int k = 0; k < 8; k++) {
        long e = base + k*512 + tid;
        if (e < EE) {
            int s = src[e];
            unsigned d = (unsigned)dst[e];
            int t = et[(size_t)e << eshift] ? 1 : 0;
            int bk = d >> 7, nl = d & 127;
            int r = atomicAdd(&cur[bk], 1);
            if (r < ECAP) region[bk*ECAP + r] = (nl << 18) | (t << 17) | s;
        }
    }
    __syncthreads();
    if (beta == NB - 1)
        for (int i = tid; i < BB; i += 512) bucketCnt[i] = cur[i];
}

// ---- k_g: per-bucket CSR + gather sums (R7/R8 shape, proven no-spill) ----
__global__ __launch_bounds__(512) void k_g(const __bf16* __restrict__ featb,
                                           const int* __restrict__ region,
                                           const int* __restrict__ bucketCnt,
                                           __bf16* __restrict__ s1b,
                                           __bf16* __restrict__ s0b,
                                           int* __restrict__ cc) {
    __shared__ int ncnt[NPB];
    __shared__ __align__(16) int csr[NPB * CSTRD];
    int b = blockIdx.x, tid = threadIdx.x;
    int cntE = min(bucketCnt[b], ECAP);
    if (tid < NPB) ncnt[tid] = 0;
    __syncthreads();
    const int* reg = region + b * ECAP;
    for (int i = tid; i < cntE; i += 512) {
        int rec = reg[i];
        int nl = rec >> 18;
        int r = atomicAdd(&ncnt[nl], 1);
        if (r < DCAP) csr[nl*CSTRD + r] = rec & 0x3ffff;
    }
    __syncthreads();

    int lane = tid & 63, wave = tid >> 6;
    int L = lane & 15, q = lane >> 4;
    int nl = wave * 16 + L;
    int n = b * NPB + nl;
    int cnt = (n < NN) ? min(ncnt[nl], DCAP) : 0;
    const int* eb = &csr[nl * CSTRD];

    float sA[16], s1[16];
    #pragma unroll
    for (int j = 0; j < 16; j++) { sA[j] = 0.f; s1[j] = 0.f; }
    int c1 = 0, i = 0;
    for (; i + 4 <= cnt; i += 4) {   // 8 outstanding 16B gathers per trip
        int e4[4];
        #pragma unroll
        for (int j = 0; j < 4; j++) e4[j] = eb[i + j];
        bf16x8 ra[4], rb[4];
        #pragma unroll
        for (int j = 0; j < 4; j++) {
            const __bf16* row = featb + (long)(e4[j] & 0x1ffff) * 64;
            ra[j] = *(const bf16x8*)(row + q*8);
            rb[j] = *(const bf16x8*)(row + 32 + q*8);
        }
        #pragma unroll
        for (int j = 0; j < 4; j++) {
            int t = (e4[j] >> 17) & 1; c1 += t;
            float ft = (float)t;
            #pragma unroll
            for (int k = 0; k < 8; k++) {
                float va = (float)ra[j][k], wa = (float)rb[j][k];
                sA[k] += va;      sA[8+k] += wa;
                s1[k] += ft*va;   s1[8+k] += ft*wa;
            }
        }
    }
    for (; i < cnt; i++) {
        int ea = eb[i];
        const __bf16* row = featb + (long)(ea & 0x1ffff) * 64;
        bf16x8 a0 = *(const bf16x8*)(row + q*8);
        bf16x8 a1 = *(const bf16x8*)(row + 32 + q*8);
        int ta = (ea >> 17) & 1; c1 += ta;
        float fa = (float)ta;
        #pragma unroll
        for (int k = 0; k < 8; k++) {
            float va = (float)a0[k], wa = (float)a1[k];
            sA[k] += va;      sA[8+k] += wa;
            s1[k] += fa*va;   s1[8+k] += fa*wa;
        }
    }
    if (n >= NN) return;
    union { bf16x8 v; __bf16 e[8]; } u;
    #pragma unroll
    for (int ch = 0; ch < 2; ch++) {
        #pragma unroll
        for (int j = 0; j < 8; j++) u.e[j] = (__bf16)s1[ch*8+j];
        *(bf16x8*)(s1b + (long)n*64 + ch*32 + q*8) = u.v;
        #pragma unroll
        for (int j = 0; j < 8; j++) u.e[j] = (__bf16)(sA[ch*8+j] - s1[ch*8+j]);
        *(bf16x8*)(s0b + (long)n*64 + ch*32 + q*8) = u.v;
    }
    if (q == 0) cc[n] = cnt | (c1 << 16);
}

// ---- k_mm2: streaming GRU+head. Wf0/Wf1/Wout in LDS (stride 68), Whh from
// L2. Transposed gates: D[m=gatedim, n=node(L)]; h -> head A-layout via shfl.
__global__ __launch_bounds__(256) void k_mm2(const __bf16* __restrict__ s1b,
                                             const __bf16* __restrict__ s0b,
                                             const __bf16* __restrict__ featb,
                                             const int* __restrict__ cc,
                                             const __bf16* __restrict__ wbn,
                                             const float* __restrict__ biasv,
                                             const float* __restrict__ bout,
                                             float* __restrict__ out) {
    __shared__ __align__(16) unsigned ldw[400 * (WSTR/2)];  // 400 rows x 34 u32
    __shared__ float bl[640];
    int tid = threadIdx.x, lane = tid & 63, wave = tid >> 6;
    int L = lane & 15, q = lane >> 4;

    // stage Wf0 (rows 0-191), Wf1 (192-383), Wout (384-399)
    const unsigned* gw = (const unsigned*)wbn;
    for (int i = tid; i < 12800; i += 256) {
        int row = i >> 5, col = i & 31;
        unsigned v = (i < 12288) ? gw[i] : gw[18432 + (i - 12288)];
        ldw[row * (WSTR/2) + col] = v;
    }
    for (int i = tid; i < 640; i += 256) bl[i] = biasv[i];
    __syncthreads();
    const __bf16* ldsW = (const __bf16*)ldw;
    const __bf16* whhg = wbn + 24576;
    f32x4 zz = {0.f, 0.f, 0.f, 0.f};
    float bo = bout[L];

    for (int t = blockIdx.x * 4 + wave; t < NN/16; t += 2048) {
        int n0 = t * 16;
        long nrow = (long)(n0 + L) * 64;
        const __bf16* r1 = s1b + nrow;
        const __bf16* r0 = s0b + nrow;
        const __bf16* fr = featb + nrow;
        bf16x8 fS1[2] = { *(const bf16x8*)(r1 + q*8), *(const bf16x8*)(r1 + 32 + q*8) };
        bf16x8 fS0[2] = { *(const bf16x8*)(r0 + q*8), *(const bf16x8*)(r0 + 32 + q*8) };
        bf16x8 fAf[2] = { *(const bf16x8*)(fr + q*8), *(const bf16x8*)(fr + 32 + q*8) };
        int cv = cc[n0 + L];
        float fc1 = (float)(cv >> 16), fc0 = (float)((cv & 0xffff) - (cv >> 16));
        // blend values: node L, dims nb*16+q*4+{0..3}
        u32x2 fw4[4];
        #pragma unroll
        for (int nb = 0; nb < 4; nb++)
            fw4[nb] = *(const u32x2*)(featb + nrow + nb*16 + q*4);

        unsigned hp[4][2];
        #pragma unroll
        for (int nb = 0; nb < 4; nb++) {
            f32x4 aR = zz, aZ = zz, aIN = zz, aHN = zz;
            #pragma unroll
            for (int g = 0; g < 3; g++) {
                int row = g*64 + nb*16 + L;
                bf16x8 w0a = *(const bf16x8*)(ldsW + row*WSTR + q*8);
                bf16x8 w0b = *(const bf16x8*)(ldsW + row*WSTR + 32 + q*8);
                bf16x8 w1a = *(const bf16x8*)(ldsW + (192+row)*WSTR + q*8);
                bf16x8 w1b = *(const bf16x8*)(ldsW + (192+row)*WSTR + 32 + q*8);
                bf16x8 wha = *(const bf16x8*)(whhg + row*64 + q*8);
                bf16x8 whb = *(const bf16x8*)(whhg + row*64 + 32 + q*8);
                if (g == 0) {
                    aR = MFMA16(w0a, fS1[0], aR,0,0,0);
                    aR = MFMA16(w0b, fS1[1], aR,0,0,0);
                    aR = MFMA16(w1a, fS0[0], aR,0,0,0);
                    aR = MFMA16(w1b, fS0[1], aR,0,0,0);
                    aR = MFMA16(wha, fAf[0], aR,0,0,0);
                    aR = MFMA16(whb, fAf[1], aR,0,0,0);
                } else if (g == 1) {
                    aZ = MFMA16(w0a, fS1[0], aZ,0,0,0);
                    aZ = MFMA16(w0b, fS1[1], aZ,0,0,0);
                    aZ = MFMA16(w1a, fS0[0], aZ,0,0,0);
                    aZ = MFMA16(w1b, fS0[1], aZ,0,0,0);
                    aZ = MFMA16(wha, fAf[0], aZ,0,0,0);
                    aZ = MFMA16(whb, fAf[1], aZ,0,0,0);
                } else {
                    aIN = MFMA16(w0a, fS1[0], aIN,0,0,0);
                    aIN = MFMA16(w0b, fS1[1], aIN,0,0,0);
                    aIN = MFMA16(w1a, fS0[0], aIN,0,0,0);
                    aIN = MFMA16(w1b, fS0[1], aIN,0,0,0);
                    aHN = MFMA16(wha, fAf[0], aHN,0,0,0);
                    aHN = MFMA16(whb, fAf[1], aHN,0,0,0);
                }
            }
            int o4 = nb*16 + q*4;
            f32x4 bAr  = *(const f32x4*)(bl + o4);
            f32x4 bAz  = *(const f32x4*)(bl + 64 + o4);
            f32x4 bAn  = *(const f32x4*)(bl + 128 + o4);
            f32x4 v0r  = *(const f32x4*)(bl + 192 + o4);
            f32x4 v0z  = *(const f32x4*)(bl + 256 + o4);
            f32x4 v0n  = *(const f32x4*)(bl + 320 + o4);
            f32x4 v1r  = *(const f32x4*)(bl + 384 + o4);
            f32x4 v1z  = *(const f32x4*)(bl + 448 + o4);
            f32x4 v1n  = *(const f32x4*)(bl + 512 + o4);
            f32x4 bhnv = *(const f32x4*)(bl + 576 + o4);
            float fvv[4] = { unpk(fw4[nb][0],0), unpk(fw4[nb][0],1),
                             unpk(fw4[nb][1],0), unpk(fw4[nb][1],1) };
            float hv[4];
            #pragma unroll
            for (int r = 0; r < 4; r++) {
                float rv = sigmoidf_(aR[r] + fc1*v0r[r] + fc0*v1r[r] + bAr[r]);
                float zv = sigmoidf_(aZ[r] + fc1*v0z[r] + fc0*v1z[r] + bAz[r]);
                float nv = tanhf_(aIN[r] + fc1*v0n[r] + fc0*v1n[r] + bAn[r]
                                  + rv*(aHN[r] + bhnv[r]));
                hv[r] = (1.0f - zv)*nv + zv*fvv[r];
            }
            hp[nb][0] = packbf(hv[0], hv[1]);
            hp[nb][1] = packbf(hv[2], hv[3]);
        }
        // head: assemble h A-frags via shfl (verified mapping, R9)
        bf16x8 Ah[2];
        int l0 = L + 16*(2*(q&1));
        int l1 = l0 + 16;
        int sel = q >> 1;
        #pragma unroll
        for (int ch = 0; ch < 2; ch++) {
            unsigned dw[4];
            unsigned a0 = __shfl((int)hp[ch*2][0], l0), b0v = __shfl((int)hp[ch*2+1][0], l0);
            dw[0] = sel ? b0v : a0;
            unsigned a1 = __shfl((int)hp[ch*2][1], l0), b1v = __shfl((int)hp[ch*2+1][1], l0);
            dw[1] = sel ? b1v : a1;
            unsigned a2 = __shfl((int)hp[ch*2][0], l1), b2v = __shfl((int)hp[ch*2+1][0], l1);
            dw[2] = sel ? b2v : a2;
            unsigned a3 = __shfl((int)hp[ch*2][1], l1), b3v = __shfl((int)hp[ch*2+1][1], l1);
            dw[3] = sel ? b3v : a3;
            union { unsigned u[4]; bf16x8 v; } c;
            c.u[0]=dw[0]; c.u[1]=dw[1]; c.u[2]=dw[2]; c.u[3]=dw[3];
            Ah[ch] = c.v;
        }
        bf16x8 Bo0 = *(const bf16x8*)(ldsW + (384+L)*WSTR + q*8);
        bf16x8 Bo1 = *(const bf16x8*)(ldsW + (384+L)*WSTR + 32 + q*8);
        f32x4 o = zz;
        o = MFMA16(Ah[0], Bo0, o,0,0,0);
        o = MFMA16(Ah[1], Bo1, o,0,0,0);
        #pragma unroll
        for (int r = 0; r < 4; r++)
            out[(long)(n0 + q*4 + r)*16 + L] = o[r] + bo;
    }
}

extern "C" void kernel_launch(void* const* d_in, const int* in_sizes, int n_in,
                              void* d_out, int out_size, void* d_ws, size_t ws_size,
                              hipStream_t stream) {
    const float* feat = (const float*)d_in[0];
    const int*   src  = (const int*)d_in[1];
    const int*   dst  = (const int*)d_in[2];
    const unsigned char* et = (const unsigned char*)d_in[3];
    const float* w0   = (const float*)d_in[4];
    const float* b0   = (const float*)d_in[5];
    const float* w1   = (const float*)d_in[6];
    const float* b1   = (const float*)d_in[7];
    const float* wih  = (const float*)d_in[8];
    const float* whh  = (const float*)d_in[9];
    const float* bih  = (const float*)d_in[10];
    const float* bhh  = (const float*)d_in[11];
    const float* wout = (const float*)d_in[12];
    const float* bout = (const float*)d_in[13];
    float* out = (float*)d_out;

    char* ws = (char*)d_ws;
    size_t off = 0;
    __bf16* featb     = (__bf16*)(ws + off); off += (size_t)NN * 64 * 2;    // 12.8 MB
    int*    region    = (int*)(ws + off);    off += (size_t)BB * ECAP * 4;  // 5.0 MB
    int*    hist      = (int*)(ws + off);    off += (size_t)NB * BB * 4;    // 766 KB
    int*    bucketCnt = (int*)(ws + off);    off += (size_t)BB * 4;
    int*    cc        = (int*)(ws + off);    off += (size_t)NN * 4;
    __bf16* s1b       = (__bf16*)(ws + off); off += (size_t)NN * 64 * 2;    // 12.8 MB
    __bf16* s0b       = (__bf16*)(ws + off); off += (size_t)NN * 64 * 2;    // 12.8 MB
    __bf16* wbn       = (__bf16*)(ws + off); off += 37888 * 2;
    float*  biasv     = (float*)(ws + off);  off += 640 * 4;
    int*    flag      = (int*)(ws + off);

    k_init<<<76 + NB + 1563, 512, 0, stream>>>(et, feat, dst, w0, b0, w1, b1,
                                               wih, whh, bih, bhh, wout,
                                               featb, wbn, biasv, hist, flag);
    k_place<<<NB, 512, 0, stream>>>(src, dst, et, flag, hist, region, bucketCnt);
    k_g<<<BB, 512, 0, stream>>>(featb, region, bucketCnt, s1b, s0b, cc);
    k_mm2<<<512, 256, 0, stream>>>(s1b, s0b, featb, cc, wbn, biasv, bout, out);
}

// Round 11
// 251.822 us; speedup vs baseline: 1.9389x; 1.2298x over previous
//
#include <hip/hip_runtime.h>

// GGNN on MI355X. N=100000, E=1000000, H=M=64, C=16.
// R10 post-mortem: k_mm2 spilled (VGPR 256, 50MB scratch writes) — full
// unrolls + batched frag loads let the compiler hoist ~70 weight loads.
// R11: tail rebuilt in the R8-proven no-spill shape (loads adjacent to MFMAs,
// accums scoped per gate, h via per-wave LDS), persistent grid-stride with
// Wf0/Wf1+biases staged once per block in LDS (stride 68), Whh/Wout from L2,
// and explicit `#pragma unroll 1` on nb/tile loops to forbid hoisting.
// Pipeline (4 launches): k_init -> k_place -> k_g -> k_mm3.

typedef __bf16 bf16x8 __attribute__((ext_vector_type(8)));
typedef float  f32x4  __attribute__((ext_vector_type(4)));
typedef int    i32x4  __attribute__((ext_vector_type(4)));

#define MFMA16 __builtin_amdgcn_mfma_f32_16x16x32_bf16
#define NN    100000
#define EE    1000000
#define BB    782      // buckets (dst >> 7)
#define NPB   128      // nodes per bucket
#define ECAP  1600     // bucket region cap (mean 1280, +9 sigma)
#define DCAP  48       // per-node degree cap
#define CSTRD 49       // CSR LDS stride (ints)
#define NB    245      // hist/place blocks (4096 edges each)
#define WSTR  68       // LDS weight row stride (bf16 elems)

__device__ __forceinline__ float sigmoidf_(float x){ return 1.0f/(1.0f+__expf(-x)); }
__device__ __forceinline__ float tanhf_(float x){ return 1.0f - 2.0f/(__expf(2.0f*x)+1.0f); }

// ---- k_init: detect / Wf+bias precompute / Whh+Wout cvt / feat cvt / hist ----
__global__ __launch_bounds__(512) void k_init(
        const unsigned char* __restrict__ et, const float* __restrict__ feat,
        const int* __restrict__ dst,
        const float* __restrict__ w0, const float* __restrict__ b0,
        const float* __restrict__ w1, const float* __restrict__ b1,
        const float* __restrict__ wih, const float* __restrict__ whh,
        const float* __restrict__ bih, const float* __restrict__ bhh,
        const float* __restrict__ wout,
        __bf16* __restrict__ featb, __bf16* __restrict__ wbn,
        float* __restrict__ biasv, int* __restrict__ hist,
        int* __restrict__ flag) {
    __shared__ int s32[BB];
    int b = blockIdx.x, tid = threadIdx.x;
    if (b == 0) {
        // dtype detect: flag=1 iff any nonzero byte at offset%4!=0 in 64KB
        const i32x4* p = (const i32x4*)et + tid * 8;  // 128B/thread
        unsigned acc = 0;
        #pragma unroll
        for (int j = 0; j < 8; j++) {
            i32x4 w = p[j];
            acc |= (unsigned)(w[0] | w[1] | w[2] | w[3]) & 0xffffff00u;
        }
        unsigned long long m = __ballot(acc != 0);
        if ((tid & 63) == 0) s32[tid >> 6] = (m != 0ULL);
        __syncthreads();
        if (tid == 0) {
            int f = 0;
            for (int i = 0; i < 8; i++) f |= s32[i];
            *flag = f;
        }
        return;
    }
    if (b < 50) {   // Wf0/Wf1 = Wih@W0/W1 (bf16); bv0/bv1 = Wih@b; bias arrays
        int idx = (b - 1) * 512 + tid;
        if (idx < 12288) {
            int g = idx >> 6, h = idx & 63;
            float a = 0.f;
            for (int m = 0; m < 64; m++) a += wih[g*64+m] * w0[m*64+h];
            wbn[idx] = (__bf16)a;
        } else if (idx < 24576) {
            int j = idx - 12288; int g = j >> 6, h = j & 63;
            float a = 0.f;
            for (int m = 0; m < 64; m++) a += wih[g*64+m] * w1[m*64+h];
            wbn[idx] = (__bf16)a;
        } else if (idx < 24768) {
            int g = idx - 24576;
            float a0 = 0.f, a1 = 0.f;
            for (int m = 0; m < 64; m++) {
                float w = wih[g*64+m]; a0 += w*b0[m]; a1 += w*b1[m];
            }
            biasv[192+g] = a0; biasv[384+g] = a1;
        } else if (idx < 24960) {
            int g = idx - 24768;   // [0:128)=r,z combined; [128:192)=bih_n
            biasv[g] = (g < 128) ? (bih[g] + bhh[g]) : bih[g];
        } else if (idx < 25024) {
            int g2 = idx - 24960;
            biasv[576+g2] = bhh[128+g2];   // bhn
        }
        return;
    }
    if (b < 76) {   // Whh (bf16) + Wout (bf16)
        int i = (b - 50) * 512 + tid;
        if (i < 12288)      wbn[24576 + i] = (__bf16)whh[i];
        else if (i < 13312) wbn[36864 + i - 12288] = (__bf16)wout[i - 12288];
        return;
    }
    if (b < 76 + NB) {   // bucket histogram, 4096 edges/block
        int blk = b - 76;
        for (int i = tid; i < BB; i += 512) s32[i] = 0;
        __syncthreads();
        long base = (long)blk * 4096;
        #pragma unroll
        for (int k = 0; k < 8; k++) {
            long e = base + k*512 + tid;
            if (e < EE) atomicAdd(&s32[((unsigned)dst[e]) >> 7], 1);
        }
        __syncthreads();
        for (int i = tid; i < BB; i += 512) hist[blk*BB + i] = s32[i];
        return;
    }
    // features f32 -> bf16, 8 elems/thread
    long i0 = ((long)(b - 76 - NB) * 512 + tid) * 8;
    if (i0 >= (long)NN * 64) return;
    f32x4 v0 = *(const f32x4*)(feat + i0);
    f32x4 v1 = *(const f32x4*)(feat + i0 + 4);
    union { __bf16 e[8]; i32x4 u; } o;
    #pragma unroll
    for (int j = 0; j < 4; j++) { o.e[j] = (__bf16)v0[j]; o.e[4+j] = (__bf16)v1[j]; }
    *(i32x4*)(featb + i0) = o.u;
}

// ---- k_place: scan hist rows < beta (register-accumulated) + place edges ----
__global__ __launch_bounds__(512) void k_place(
        const int* __restrict__ src, const int* __restrict__ dst,
        const unsigned char* __restrict__ et, const int* __restrict__ flag,
        const int* __restrict__ hist, int* __restrict__ region,
        int* __restrict__ bucketCnt) {
    __shared__ int cur[BB];
    int beta = blockIdx.x, tid = threadIdx.x;
    int a0 = 0, a1 = 0;
    int i1 = tid + 512;
    for (int r = 0; r < beta; r++) {
        a0 += hist[r*BB + tid];
        if (i1 < BB) a1 += hist[r*BB + i1];
    }
    cur[tid] = a0;
    if (i1 < BB) cur[i1] = a1;
    __syncthreads();
    int eshift = (*flag) ? 0 : 2;  // byte stride: 1 (bool) or 4 (int32 LSB)
    long base = (long)beta * 4096;
    #pragma unroll
    for (int k = 0; k < 8; k++) {
        long e = base + k*512 + tid;
        if (e < EE) {
            int s = src[e];
            unsigned d = (unsigned)dst[e];
            int t = et[(size_t)e << eshift] ? 1 : 0;
            int bk = d >> 7, nl = d & 127;
            int r = atomicAdd(&cur[bk], 1);
            if (r < ECAP) region[bk*ECAP + r] = (nl << 18) | (t << 17) | s;
        }
    }
    __syncthreads();
    if (beta == NB - 1)
        for (int i = tid; i < BB; i += 512) bucketCnt[i] = cur[i];
}

// ---- k_g: per-bucket CSR + gather sums (proven no-spill shape) ----
__global__ __launch_bounds__(512) void k_g(const __bf16* __restrict__ featb,
                                           const int* __restrict__ region,
                                           const int* __restrict__ bucketCnt,
                                           __bf16* __restrict__ s1b,
                                           __bf16* __restrict__ s0b,
                                           int* __restrict__ cc) {
    __shared__ int ncnt[NPB];
    __shared__ __align__(16) int csr[NPB * CSTRD];
    int b = blockIdx.x, tid = threadIdx.x;
    int cntE = min(bucketCnt[b], ECAP);
    if (tid < NPB) ncnt[tid] = 0;
    __syncthreads();
    const int* reg = region + b * ECAP;
    for (int i = tid; i < cntE; i += 512) {
        int rec = reg[i];
        int nl = rec >> 18;
        int r = atomicAdd(&ncnt[nl], 1);
        if (r < DCAP) csr[nl*CSTRD + r] = rec & 0x3ffff;
    }
    __syncthreads();

    int lane = tid & 63, wave = tid >> 6;
    int L = lane & 15, q = lane >> 4;
    int nl = wave * 16 + L;
    int n = b * NPB + nl;
    int cnt = (n < NN) ? min(ncnt[nl], DCAP) : 0;
    const int* eb = &csr[nl * CSTRD];

    float sA[16], s1[16];
    #pragma unroll
    for (int j = 0; j < 16; j++) { sA[j] = 0.f; s1[j] = 0.f; }
    int c1 = 0, i = 0;
    for (; i + 4 <= cnt; i += 4) {   // 8 outstanding 16B gathers per trip
        int e4[4];
        #pragma unroll
        for (int j = 0; j < 4; j++) e4[j] = eb[i + j];
        bf16x8 ra[4], rb[4];
        #pragma unroll
        for (int j = 0; j < 4; j++) {
            const __bf16* row = featb + (long)(e4[j] & 0x1ffff) * 64;
            ra[j] = *(const bf16x8*)(row + q*8);
            rb[j] = *(const bf16x8*)(row + 32 + q*8);
        }
        #pragma unroll
        for (int j = 0; j < 4; j++) {
            int t = (e4[j] >> 17) & 1; c1 += t;
            float ft = (float)t;
            #pragma unroll
            for (int k = 0; k < 8; k++) {
                float va = (float)ra[j][k], wa = (float)rb[j][k];
                sA[k] += va;      sA[8+k] += wa;
                s1[k] += ft*va;   s1[8+k] += ft*wa;
            }
        }
    }
    for (; i < cnt; i++) {
        int ea = eb[i];
        const __bf16* row = featb + (long)(ea & 0x1ffff) * 64;
        bf16x8 a0 = *(const bf16x8*)(row + q*8);
        bf16x8 a1 = *(const bf16x8*)(row + 32 + q*8);
        int ta = (ea >> 17) & 1; c1 += ta;
        float fa = (float)ta;
        #pragma unroll
        for (int k = 0; k < 8; k++) {
            float va = (float)a0[k], wa = (float)a1[k];
            sA[k] += va;      sA[8+k] += wa;
            s1[k] += fa*va;   s1[8+k] += fa*wa;
        }
    }
    if (n >= NN) return;
    union { bf16x8 v; __bf16 e[8]; } u;
    #pragma unroll
    for (int ch = 0; ch < 2; ch++) {
        #pragma unroll
        for (int j = 0; j < 8; j++) u.e[j] = (__bf16)s1[ch*8+j];
        *(bf16x8*)(s1b + (long)n*64 + ch*32 + q*8) = u.v;
        #pragma unroll
        for (int j = 0; j < 8; j++) u.e[j] = (__bf16)(sA[ch*8+j] - s1[ch*8+j]);
        *(bf16x8*)(s0b + (long)n*64 + ch*32 + q*8) = u.v;
    }
    if (q == 0) cc[n] = cnt | (c1 << 16);
}

// ---- k_mm3: streaming GRU+head, R8-proven shape. Wf0/Wf1+biases in LDS
// (one-time stage), Whh/Wout from L2. unroll-1 loops to forbid hoisting. ----
__global__ __launch_bounds__(256) void k_mm3(const __bf16* __restrict__ s1b,
                                             const __bf16* __restrict__ s0b,
                                             const __bf16* __restrict__ featb,
                                             const int* __restrict__ cc,
                                             const __bf16* __restrict__ wbn,
                                             const float* __restrict__ biasv,
                                             const float* __restrict__ bout,
                                             float* __restrict__ out) {
    __shared__ __align__(16) unsigned ldw[384 * (WSTR/2)];  // Wf0|Wf1, 52224 B
    __shared__ float bl[640];                               // 2560 B
    __shared__ __bf16 sHa[4][16 * 72];                      // 9216 B  (total 64000)
    int tid = threadIdx.x, lane = tid & 63, wave = tid >> 6;
    int L = lane & 15, q = lane >> 4;

    const unsigned* gw = (const unsigned*)wbn;
    for (int i = tid; i < 12288; i += 256) {
        int row = i >> 5, col = i & 31;
        ldw[row * (WSTR/2) + col] = gw[i];
    }
    for (int i = tid; i < 640; i += 256) bl[i] = biasv[i];
    __syncthreads();
    const __bf16* ldsW = (const __bf16*)ldw;
    const __bf16* whhg = wbn + 24576;
    const __bf16* wo   = wbn + 36864;
    __bf16* sH = sHa[wave];
    f32x4 zz = {0.f, 0.f, 0.f, 0.f};
    float bo = bout[L];

    #pragma unroll 1
    for (int t = blockIdx.x * 4 + wave; t < NN/16; t += 2048) {
        int n0 = t * 16;
        long nrow = (long)(n0 + L) * 64;
        const __bf16* r1 = s1b + nrow;
        const __bf16* r0 = s0b + nrow;
        const __bf16* fr = featb + nrow;
        bf16x8 fS1[2] = { *(const bf16x8*)(r1 + q*8), *(const bf16x8*)(r1 + 32 + q*8) };
        bf16x8 fS0[2] = { *(const bf16x8*)(r0 + q*8), *(const bf16x8*)(r0 + 32 + q*8) };
        bf16x8 fAf[2] = { *(const bf16x8*)(fr + q*8), *(const bf16x8*)(fr + 32 + q*8) };
        float fc1[4], fc0[4];
        #pragma unroll
        for (int r = 0; r < 4; r++) {
            int cv = cc[n0 + q*4 + r];
            int c1 = cv >> 16, ct = cv & 0xffff;
            fc1[r] = (float)c1; fc0[r] = (float)(ct - c1);
        }

        #pragma unroll 1
        for (int nb = 0; nb < 4; nb++) {
            int gr = nb*16 + L;
            f32x4 aR = zz, aZ = zz, aIN = zz, aHN = zz;
            {   // gate r: rows gr
                int ro = gr*WSTR + q*8, rg = gr*64 + q*8;
                aR = MFMA16(fS1[0], *(const bf16x8*)(ldsW + ro), aR,0,0,0);
                aR = MFMA16(fS1[1], *(const bf16x8*)(ldsW + ro + 32), aR,0,0,0);
                aR = MFMA16(fS0[0], *(const bf16x8*)(ldsW + 192*WSTR + ro), aR,0,0,0);
                aR = MFMA16(fS0[1], *(const bf16x8*)(ldsW + 192*WSTR + ro + 32), aR,0,0,0);
                aR = MFMA16(fAf[0], *(const bf16x8*)(whhg + rg), aR,0,0,0);
                aR = MFMA16(fAf[1], *(const bf16x8*)(whhg + rg + 32), aR,0,0,0);
            }
            {   // gate z: rows 64+gr
                int ro = (64+gr)*WSTR + q*8, rg = (64+gr)*64 + q*8;
                aZ = MFMA16(fS1[0], *(const bf16x8*)(ldsW + ro), aZ,0,0,0);
                aZ = MFMA16(fS1[1], *(const bf16x8*)(ldsW + ro + 32), aZ,0,0,0);
                aZ = MFMA16(fS0[0], *(const bf16x8*)(ldsW + 192*WSTR + ro), aZ,0,0,0);
                aZ = MFMA16(fS0[1], *(const bf16x8*)(ldsW + 192*WSTR + ro + 32), aZ,0,0,0);
                aZ = MFMA16(fAf[0], *(const bf16x8*)(whhg + rg), aZ,0,0,0);
                aZ = MFMA16(fAf[1], *(const bf16x8*)(whhg + rg + 32), aZ,0,0,0);
            }
            {   // gate n: rows 128+gr (i-part and h-part separate)
                int ro = (128+gr)*WSTR + q*8, rg = (128+gr)*64 + q*8;
                aIN = MFMA16(fS1[0], *(const bf16x8*)(ldsW + ro), aIN,0,0,0);
                aIN = MFMA16(fS1[1], *(const bf16x8*)(ldsW + ro + 32), aIN,0,0,0);
                aIN = MFMA16(fS0[0], *(const bf16x8*)(ldsW + 192*WSTR + ro), aIN,0,0,0);
                aIN = MFMA16(fS0[1], *(const bf16x8*)(ldsW + 192*WSTR + ro + 32), aIN,0,0,0);
                aHN = MFMA16(fAf[0], *(const bf16x8*)(whhg + rg), aHN,0,0,0);
                aHN = MFMA16(fAf[1], *(const bf16x8*)(whhg + rg + 32), aHN,0,0,0);
            }
            float brz = bl[gr],        bzz = bl[64 + gr];
            float bin = bl[128 + gr],  bhn = bl[576 + gr];
            float v0r = bl[192 + gr],  v0z = bl[256 + gr], v0n = bl[320 + gr];
            float v1r = bl[384 + gr],  v1z = bl[448 + gr], v1n = bl[512 + gr];
            #pragma unroll
            for (int r = 0; r < 4; r++) {
                float fv = (float)featb[(long)(n0 + q*4 + r)*64 + gr];
                float rv = sigmoidf_(aR[r] + fc1[r]*v0r + fc0[r]*v1r + brz);
                float zv = sigmoidf_(aZ[r] + fc1[r]*v0z + fc0[r]*v1z + bzz);
                float nv = tanhf_(aIN[r] + fc1[r]*v0n + fc0[r]*v1n + bin
                                  + rv*(aHN[r] + bhn));
                sH[(q*4 + r)*72 + gr] = (__bf16)((1.0f - zv)*nv + zv*fv);
            }
        }
        // head: out = h @ Wout^T + bout (same-wave LDS, in-order)
        bf16x8 Ah0 = *(const bf16x8*)&sH[L*72 + q*8];
        bf16x8 Ah1 = *(const bf16x8*)&sH[L*72 + 32 + q*8];
        bf16x8 Bo0 = *(const bf16x8*)(wo + L*64 + q*8);
        bf16x8 Bo1 = *(const bf16x8*)(wo + L*64 + 32 + q*8);
        f32x4 o = zz;
        o = MFMA16(Ah0, Bo0, o,0,0,0);
        o = MFMA16(Ah1, Bo1, o,0,0,0);
        #pragma unroll
        for (int r = 0; r < 4; r++)
            out[(long)(n0 + q*4 + r)*16 + L] = o[r] + bo;
    }
}

extern "C" void kernel_launch(void* const* d_in, const int* in_sizes, int n_in,
                              void* d_out, int out_size, void* d_ws, size_t ws_size,
                              hipStream_t stream) {
    const float* feat = (const float*)d_in[0];
    const int*   src  = (const int*)d_in[1];
    const int*   dst  = (const int*)d_in[2];
    const unsigned char* et = (const unsigned char*)d_in[3];
    const float* w0   = (const float*)d_in[4];
    const float* b0   = (const float*)d_in[5];
    const float* w1   = (const float*)d_in[6];
    const float* b1   = (const float*)d_in[7];
    const float* wih  = (const float*)d_in[8];
    const float* whh  = (const float*)d_in[9];
    const float* bih  = (const float*)d_in[10];
    const float* bhh  = (const float*)d_in[11];
    const float* wout = (const float*)d_in[12];
    const float* bout = (const float*)d_in[13];
    float* out = (float*)d_out;

    char* ws = (char*)d_ws;
    size_t off = 0;
    __bf16* featb     = (__bf16*)(ws + off); off += (size_t)NN * 64 * 2;    // 12.8 MB
    int*    region    = (int*)(ws + off);    off += (size_t)BB * ECAP * 4;  // 5.0 MB
    int*    hist      = (int*)(ws + off);    off += (size_t)NB * BB * 4;    // 766 KB
    int*    bucketCnt = (int*)(ws + off);    off += (size_t)BB * 4;
    int*    cc        = (int*)(ws + off);    off += (size_t)NN * 4;
    __bf16* s1b       = (__bf16*)(ws + off); off += (size_t)NN * 64 * 2;    // 12.8 MB
    __bf16* s0b       = (__bf16*)(ws + off); off += (size_t)NN * 64 * 2;    // 12.8 MB
    __bf16* wbn       = (__bf16*)(ws + off); off += 37888 * 2;
    float*  biasv     = (float*)(ws + off);  off += 640 * 4;
    int*    flag      = (int*)(ws + off);

    k_init<<<76 + NB + 1563, 512, 0, stream>>>(et, feat, dst, w0, b0, w1, b1,
                                               wih, whh, bih, bhh, wout,
                                               featb, wbn, biasv, hist, flag);
    k_place<<<NB, 512, 0, stream>>>(src, dst, et, flag, hist, region, bucketCnt);
    k_g<<<BB, 512, 0, stream>>>(featb, region, bucketCnt, s1b, s0b, cc);
    k_mm3<<<512, 256, 0, stream>>>(s1b, s0b, featb, cc, wbn, biasv, bout, out);
}